// Round 17
// baseline (417.834 us; speedup 1.0000x reference)
//
#include <hip/hip_runtime.h>

// ---------------- constants ----------------
#define S      4096
#define DM     1024
#define NB     4
#define NH     16
#define HDIM   64
#define MTOT   (NB * S)          // 16384
#define DS     ((long)DM * S)    // 4,194,304
#define MH     2304              // padded half-rows for Mc2 (2049 used)
#define KH     2112              // folded K for Mc2 (2049 used)
#define KH2    2112              // folded K for even/odd G split (2049 used)
#define MEO    2048              // even/odd GEMM rows (n=0..2047; n=2048 special)

typedef __attribute__((ext_vector_type(8))) short short8;
typedef __attribute__((ext_vector_type(4))) float f32x4;
typedef __attribute__((ext_vector_type(8))) unsigned short u16x8;
typedef __attribute__((ext_vector_type(4))) unsigned short u16x4;

__device__ __forceinline__ unsigned short f2bf(float f) {
  union { float f; unsigned u; } v; v.f = f;
  unsigned r = v.u + 0x7fffu + ((v.u >> 16) & 1u);   // RNE
  return (unsigned short)(r >> 16);
}
__device__ __forceinline__ float bf2f(short h) {
  union { unsigned u; float f; } v; v.u = ((unsigned)(unsigned short)h) << 16;
  return v.f;
}

#define GLOAD(gp, lp) __builtin_amdgcn_global_load_lds( \
    (const __attribute__((address_space(1))) void*)(gp), \
    (__attribute__((address_space(3))) void*)(lp), 16, 0, 0)

#define SBAR() do { asm volatile("" ::: "memory"); __builtin_amdgcn_s_barrier(); \
                    asm volatile("" ::: "memory"); } while (0)
#define WAITL0() asm volatile("s_waitcnt lgkmcnt(0)" ::: "memory")

// LDS swizzle for 64B-row tiles: XOR byte bits 4-5 with row bits 1-2 (byte bits 7-8).
#define SWZ(o) ((o) ^ ((((o) >> 7) & 3) << 4))

// ---------------- small kernels ----------------

// merged tables + g (block-local tables; identical fp formulas -> deterministic)
__global__ void k_tabg(const float* __restrict__ fd, const float* __restrict__ alpha,
                       const float* __restrict__ fsc,
                       float* __restrict__ cos_tab, float* __restrict__ c_arr,
                       float* __restrict__ g) {
  const float twopi = 6.28318530717958647692f;
  float aa = alpha[0] + fsc[0] * (fd[0] - 1.5f);
  int bx = blockIdx.x;
  if (bx < 16) {
    int k = bx * 256 + threadIdx.x;
    cos_tab[k] = cosf(twopi * ((float)k / (float)S));
    int kk = (k <= S / 2) ? k : (S - k);
    float af = (float)kk / (float)S;
    c_arr[k] = cosf(aa * atanf(logf(af + 1e-10f)));
    return;
  }
  __shared__ float sct[S];
  __shared__ float sc[S];
  __shared__ float red[16][17];
  for (int i = threadIdx.x; i < S; i += 256) {
    sct[i] = cosf(twopi * ((float)i / (float)S));
    int kk = (i <= S / 2) ? i : (S - i);
    float af = (float)kk / (float)S;
    sc[i] = cosf(aa * atanf(logf(af + 1e-10f)));
  }
  __syncthreads();
  int jl = threadIdx.x >> 4, r = threadIdx.x & 15;
  int j = (bx - 16) * 16 + jl;
  float acc = 0.f;
#pragma unroll 4
  for (int i = 0; i < 256; ++i) {
    int k = r + 16 * i;
    acc += sc[k] * sct[(j * k) & (S - 1)];
  }
  red[jl][r] = acc;
  __syncthreads();
  if (r == 0) {
    float s = 0.f;
#pragma unroll
    for (int i = 0; i < 16; ++i) s += red[jl][i];
    g[j] = s * (1.f / (float)S);
  }
}

// merged foldT + transW4 + buildEO.
// bx<33: fold x->uv tile; 33<=bx<49: transW tile; bx>=49: Ge/Go chunk.
__global__ void k_prep(const float* __restrict__ x, short* __restrict__ uv,
                       const float* __restrict__ W0, const float* __restrict__ W1,
                       const float* __restrict__ W2, const float* __restrict__ W3,
                       short* __restrict__ WT,
                       const float* __restrict__ g, short* __restrict__ Ge) {
  __shared__ float sh[2 * 64 * 65];
  int bx = blockIdx.x, by = blockIdx.y, bz = blockIdx.z;
  int t = threadIdx.x;
  if (bx >= 49) {
    long lin = (long)(bx - 49) + 54L * (by + 16L * bz);
    long i8 = (lin * 256 + t) * 8;
    if (i8 >= (long)MEO * KH2) return;
    int n = (int)(i8 / KH2);
    int m = (int)(i8 % KH2);
    u16x8 ev, ov;
#pragma unroll
    for (int j = 0; j < 8; ++j) {
      int mm = m + j;
      float e, o;
      if (mm == 0)            { e = g[n]; o = 0.f; }
      else if (mm == 2048)    { e = g[(n + 2048) & (S - 1)]; o = 0.f; }
      else if (mm > 2048)     { e = 0.f; o = 0.f; }
      else {
        float a = g[(n - mm) & (S - 1)], b = g[(n + mm) & (S - 1)];
        e = 0.5f * (a + b); o = 0.5f * (a - b);
      }
      ev[j] = f2bf(e); ov[j] = f2bf(o);
    }
    *(u16x8*)(Ge + i8) = ev;
    *(u16x8*)(Ge + (long)MEO * KH2 + i8) = ov;
    return;
  }
  int r = t >> 4, c4 = (t & 15) * 4;
  if (bx >= 33) {
    float (*tile)[65] = (float(*)[65])sh;
    const float* W = (bz == 0) ? W0 : ((bz == 1) ? W1 : ((bz == 2) ? W2 : W3));
    short* WTo = WT + (size_t)bz * DM * DM;
    int k0 = (bx - 33) * 64, n0 = by * 64;
    const float* ip = W + (long)k0 * DM + n0;
#pragma unroll
    for (int rr = 0; rr < 4; ++rr) {
      float4 v = *(const float4*)(ip + (long)(r + rr * 16) * DM + c4);
      tile[r + rr * 16][c4 + 0] = v.x;
      tile[r + rr * 16][c4 + 1] = v.y;
      tile[r + rr * 16][c4 + 2] = v.z;
      tile[r + rr * 16][c4 + 3] = v.w;
    }
    __syncthreads();
    int k_loc = t & 63, nq = t >> 6;
    short* op = WTo + (long)n0 * DM + k0;
#pragma unroll
    for (int i = 0; i < 16; ++i) {
      int n_loc = nq * 16 + i;
      op[(long)n_loc * DM + k_loc] = (short)f2bf(tile[k_loc][n_loc]);
    }
    return;
  }
  float (*tp)[65] = (float(*)[65])sh;
  float (*tm)[65] = (float(*)[65])(sh + 64 * 65);
  int m0 = bx * 64, d0 = by * 64, b = bz;
#pragma unroll
  for (int rr = 0; rr < 4; ++rr) {
    int m = m0 + r + rr * 16;
    float4 vp = *(const float4*)(x + ((long)(b * S + m)) * DM + d0 + c4);
    int ms = (S - m) & (S - 1);
    float4 vm = *(const float4*)(x + ((long)(b * S + ms)) * DM + d0 + c4);
    tp[r + rr * 16][c4 + 0] = vp.x; tp[r + rr * 16][c4 + 1] = vp.y;
    tp[r + rr * 16][c4 + 2] = vp.z; tp[r + rr * 16][c4 + 3] = vp.w;
    tm[r + rr * 16][c4 + 0] = vm.x; tm[r + rr * 16][c4 + 1] = vm.y;
    tm[r + rr * 16][c4 + 2] = vm.z; tm[r + rr * 16][c4 + 3] = vm.w;
  }
  __syncthreads();
  int m_loc = t & 63, dq = t >> 6;
#pragma unroll
  for (int i = 0; i < 16; ++i) {
    int d_loc = dq * 16 + i;
    int m = m0 + m_loc;
    float P = tp[m_loc][d_loc], M = tm[m_loc][d_loc];
    float u, v;
    if (m == 0 || m == 2048) { u = P; v = 0.f; }
    else if (m > 2048)       { u = 0.f; v = 0.f; }
    else                     { u = P + M; v = P - M; }
    long base = ((long)(b * DM + d0 + d_loc)) * KH2 + m;
    uv[base] = (short)f2bf(u);
    uv[base + (long)4 * DM * KH2] = (short)f2bf(v);
  }
}

// merged: blocks [0,4096): unfold AB -> Xs; blocks [4096,8192): row n=2048 dot
__global__ void k_unfold2(const short* __restrict__ AB, const float* __restrict__ g,
                          const short* __restrict__ uv, short* __restrict__ Xs) {
  __shared__ float red[256];
  int bx = blockIdx.x;
  if (bx < 4096) {
    long i8 = ((long)bx * 256 + threadIdx.x) * 8;
    int b = (int)(i8 >> 21);             // MEO*DM = 2^21
    long rr = i8 & ((1L << 21) - 1);
    int n = (int)(rr >> 10);
    int d = (int)(rr & (DM - 1));
    u16x8 av = *(const u16x8*)(AB + i8);
    u16x8 bv = *(const u16x8*)(AB + ((long)4 * MEO * DM) + i8);
    u16x8 sv, dv;
#pragma unroll
    for (int j = 0; j < 8; ++j) {
      float A = bf2f((short)av[j]), B = bf2f((short)bv[j]);
      sv[j] = f2bf(A + B);
      dv[j] = f2bf(A - B);
    }
    *(u16x8*)(Xs + ((long)b * S + n) * DM + d) = sv;
    if (n > 0)
      *(u16x8*)(Xs + ((long)b * S + (S - n)) * DM + d) = dv;
  } else {
    int bd = bx - 4096;                  // 0..NB*DM-1
    int b = bd >> 10, d = bd & (DM - 1);
    const short* up = uv + ((long)(b * DM + d)) * KH2;
    int t = threadIdx.x;
    float acc = 0.f;
    for (int m = t; m <= 2048; m += 256)
      acc += g[2048 - m] * bf2f(up[m]);
    red[t] = acc;
    __syncthreads();
    for (int sh = 128; sh > 0; sh >>= 1) {
      if (t < sh) red[t] += red[t + sh];
      __syncthreads();
    }
    if (t == 0) Xs[((long)b * S + 2048) * DM + d] = (short)f2bf(red[0]);
  }
}

// fused logits+head-softmax. Q,K in natural [(b,s)][DM] layout.
__global__ void k_logsoft(const short* __restrict__ Q, const short* __restrict__ K,
                          float* __restrict__ w) {
  int idx = blockIdx.x * 16 + (threadIdx.x >> 4);   // (b,s) 0..16383
  int h = threadIdx.x & 15;
  const short* q = Q + (long)idx * DM + h * HDIM;
  const short* k = K + (long)idx * DM + h * HDIM;
  float acc = 0.f;
#pragma unroll
  for (int jj = 0; jj < 8; ++jj) {
    u16x8 qa = *(const u16x8*)(q + jj * 8);
    u16x8 ka = *(const u16x8*)(k + jj * 8);
#pragma unroll
    for (int l = 0; l < 8; ++l) acc += bf2f((short)qa[l]) * bf2f((short)ka[l]);
  }
  acc *= 0.125f;
  float m = acc;
#pragma unroll
  for (int d = 1; d < 16; d <<= 1) m = fmaxf(m, __shfl_xor(m, d, 16));
  float e = expf(acc - m);
  float ssum = e;
#pragma unroll
  for (int d = 1; d < 16; d <<= 1) ssum += __shfl_xor(ssum, d, 16);
  int b = idx >> 12, s = idx & (S - 1);
  w[((long)b * NH + h) * S + s] = e / ssum;
}

// merged attfold2 + buildM2. bx<33: attend+fold tile; bx>=33: buildM2 chunk.
__global__ void k_attfoldM2(const short* __restrict__ V, const float* __restrict__ wsm,
                            short* __restrict__ A2t,
                            const float* __restrict__ cos_tab, short* __restrict__ Mc2) {
  int bx = blockIdx.x, by = blockIdx.y, bz = blockIdx.z;
  if (bx >= 33) {
    long lin = (long)(bx - 33) + 38L * (by + 16L * bz);   // 0..2431
    long i8 = (lin * 256 + threadIdx.x) * 8;
    if (i8 >= (long)MH * KH) return;
    int n = (int)(i8 / KH);
    int m = (int)(i8 % KH);
    u16x8 mv;
#pragma unroll
    for (int j = 0; j < 8; ++j) {
      int mm = m + j;
      float vv = (mm <= 2048) ? cos_tab[(n * mm) & (S - 1)] * 0.015625f : 0.f;
      mv[j] = f2bf(vv);
    }
    *(u16x8*)(Mc2 + i8) = mv;
    return;
  }
  __shared__ float t1[64][65];
  __shared__ float t2[64][65];
  __shared__ float w1[64], w2[64];
  int m0 = bx * 64, d0 = by * 64, b = bz;
  int t = threadIdx.x;
  int h0 = d0 >> 6;
  if (t < 64) {
    int m = m0 + t;
    const float* wp = wsm + ((long)b * NH + h0) * S;
    w1[t] = wp[m & (S - 1)];
    w2[t] = wp[(S - m) & (S - 1)];
  }
  int r = t >> 4, c4 = (t & 15) * 4;
#pragma unroll
  for (int rr = 0; rr < 4; ++rr) {
    int i = r + rr * 16;
    int m = m0 + i;
    u16x4 a = *(const u16x4*)(V + ((long)(b * S + (m & (S - 1)))) * DM + d0 + c4);
    u16x4 bb = *(const u16x4*)(V + ((long)(b * S + ((S - m) & (S - 1)))) * DM + d0 + c4);
#pragma unroll
    for (int l = 0; l < 4; ++l) {
      t1[i][c4 + l] = bf2f((short)a[l]);
      t2[i][c4 + l] = bf2f((short)bb[l]);
    }
  }
  __syncthreads();
  int i_loc = t & 63, jq = t >> 6;
  int m = m0 + i_loc;
#pragma unroll
  for (int jj = 0; jj < 16; ++jj) {
    int j = jq * 16 + jj;
    float rv;
    if (m == 0 || m == 2048) rv = w1[i_loc] * t1[i_loc][j];
    else if (m < 2048)       rv = w1[i_loc] * t1[i_loc][j] + w2[i_loc] * t2[i_loc][j];
    else                     rv = 0.f;
    A2t[((long)(b * DM + d0 + j)) * KH + m] = (short)f2bf(rv);
  }
}

// ---------------- 128x128 4-wave GEMM (64 KiB LDS -> 2 blocks/CU) ----------------
// C = A @ B ; A row-major [M,K] bf16, B TRANSPOSED as Bt [N,K] bf16, ld = K.
// Same proven schedule as the 256^2 version: 4 phases/K-tile, vmcnt(6), SWZ.
// AMIR: A rows via even-symmetry mirror.  ASEL: A base = A + (bz>>2)*aBatch.
// EPI 0: bf16 C[M,N] per-batch.  EPI 2: fp32 C + bias + resid.
// EPI 4: QKV natural layout — rows=(b,s), col=dout; Cb/Cb2/Cb3 by col>>10.
template <int EPI, int AMIR = 0, int ASEL = 0>
__global__ __launch_bounds__(256, 2) void gemm4(
    const short* __restrict__ A, const short* __restrict__ Bt,
    short* __restrict__ Cb, short* __restrict__ Cb2, short* __restrict__ Cb3,
    float* __restrict__ Cf,
    const float* __restrict__ bias, const float* __restrict__ bias2,
    const float* __restrict__ bias3,
    const float* __restrict__ bsc, const float* __restrict__ resid,
    int M, int N, int K, long aBatch, long bBatch, long cBatch) {
  __shared__ __align__(16) short SH[32768];   // 64 KiB: A 4x8KB then B 4x8KB
  auto Ab = [&](int buf, int ks) { return SH + (buf * 2 + ks) * 4096; };
  auto Bb = [&](int buf, int ks) { return SH + 16384 + (buf * 2 + ks) * 4096; };

  const int gx = gridDim.x, gy = gridDim.y;
  const int nwg = gx * gy * gridDim.z;
  int lin = blockIdx.x + gx * (blockIdx.y + gy * blockIdx.z);
  int swz = lin;
  if ((nwg & 7) == 0) {
    const int cpx = nwg >> 3;
    swz = (lin & 7) * cpx + (lin >> 3);
  }
  const int NTN = N >> 7;
  const int NTM = M >> 7;
  const int ntile = swz % NTN;
  const int rest = swz / NTN;
  const int mtile = rest % NTM;
  const int bz = rest / NTM;

  const short* Ag = ASEL ? (A + (long)(bz >> 2) * aBatch) : (A + (long)bz * aBatch);
  const short* Bg = Bt + (long)bz * bBatch;
  const int m0 = mtile << 7, n0 = ntile << 7;
  const int tid = threadIdx.x;
  const int lane = tid & 63;
  const int wid = tid >> 6;
  const int wm = wid >> 1, wn = wid & 1;

  const int o0 = tid * 16, o1 = o0 + 4096;
  const int lo0 = SWZ(o0), lo1 = SWZ(o1);
  const int srow[2] = {lo0 >> 6, lo1 >> 6};
  const int scol[2] = {(lo0 & 63) >> 1, (lo1 & 63) >> 1};

  const short* bA[2];
  const short* bB[2];
#pragma unroll
  for (int j = 0; j < 2; ++j) {
    if (AMIR) {
      int grow = m0 + srow[j];
      int b_ = grow >> 12, s_ = grow & (S - 1);
      int sm = (s_ <= 2048) ? s_ : (4096 - s_);
      bA[j] = Ag + ((long)b_ * MH + sm) * K + scol[j];
    } else {
      bA[j] = Ag + (long)(m0 + srow[j]) * K + scol[j];
    }
    bB[j] = Bg + (long)(n0 + srow[j]) * K + scol[j];
  }

  f32x4 acc[4][4];
#pragma unroll
  for (int i = 0; i < 4; ++i)
#pragma unroll
    for (int j = 0; j < 4; ++j) acc[i][j] = (f32x4){0.f, 0.f, 0.f, 0.f};

  const int NT = K >> 6;
  auto stage = [&](int h) {
    const int tau = h >> 2, q = h & 3;
    const int ks = q >> 1;
    const long k0 = (long)tau * 64 + ks * 32;
    const int dbase = (q & 1) * 32768 + (((tau & 1) << 1) + ks) * 8192;
    const short* b0 = (q & 1) ? bB[0] : bA[0];
    const short* b1 = (q & 1) ? bB[1] : bA[1];
    GLOAD(b0 + k0, (short*)((char*)SH + dbase + o0));
    GLOAD(b1 + k0, (short*)((char*)SH + dbase + o1));
  };

#pragma unroll
  for (int h = 0; h < 7; ++h) stage(h);
  asm volatile("s_waitcnt vmcnt(6)" ::: "memory");
  SBAR();

  short8 bf[4];
  for (int t = 0; t < NT; ++t) {
    const int buf = t & 1;
#pragma unroll
    for (int p = 0; p < 4; ++p) {
      const int ks = p >> 1, mh = p & 1;
      short8 af[2];
      {
        const short* Ah = Ab(buf, ks);
        const int kb = (lane >> 4) * 16;
        const int r0 = wm * 64 + mh * 32 + (lane & 15);
#pragma unroll
        for (int i = 0; i < 2; ++i) {
          int byte = (r0 + i * 16) * 64 + kb;
          byte = SWZ(byte);
          af[i] = *(const short8*)((const char*)Ah + byte);
        }
        if (mh == 0) {
          const short* Bh = Bb(buf, ks);
          const int c0 = wn * 64 + (lane & 15);
#pragma unroll
          for (int j = 0; j < 4; ++j) {
            int byte = (c0 + j * 16) * 64 + kb;
            byte = SWZ(byte);
            bf[j] = *(const short8*)((const char*)Bh + byte);
          }
        }
      }
      { const int h = 4 * t + p + 7; if (h < 4 * NT) stage(h); }
      SBAR();
      WAITL0();
      __builtin_amdgcn_s_setprio(1);
#pragma unroll
      for (int i = 0; i < 2; ++i)
#pragma unroll
        for (int j = 0; j < 4; ++j)
          acc[mh * 2 + i][j] = __builtin_amdgcn_mfma_f32_16x16x32_bf16(
              af[i], bf[j], acc[mh * 2 + i][j], 0, 0, 0);
      __builtin_amdgcn_s_setprio(0);
      if (p == 3) {
        if (t < NT - 2) {
          asm volatile("s_waitcnt vmcnt(6)" ::: "memory");
        } else if (t == NT - 2) {
          asm volatile("s_waitcnt vmcnt(0)" ::: "memory");
        }
      }
      SBAR();
    }
  }

  const int rl = (lane >> 4) << 2;
#pragma unroll
  for (int f = 0; f < 4; ++f) {
    const int rbase = m0 + wm * 64 + f * 16 + rl;
#pragma unroll
    for (int j = 0; j < 4; ++j) {
      const int col = n0 + wn * 64 + j * 16 + (lane & 15);
      f32x4 a = acc[f][j];
      if constexpr (EPI == 0) {
        short* cp = Cb + (long)bz * cBatch;
#pragma unroll
        for (int r = 0; r < 4; ++r)
          cp[(long)(rbase + r) * N + col] = (short)f2bf(a[r]);
      } else if constexpr (EPI == 4) {
        const int pidx = col >> 10;
        const int dcol = col & (DM - 1);
        short* Cp = (pidx == 0) ? Cb : ((pidx == 1) ? Cb2 : Cb3);
        const float* bp = (pidx == 0) ? bias : ((pidx == 1) ? bias2 : bias3);
        const float bi = bp[dcol] * (bsc ? bsc[0] : 1.f);
#pragma unroll
        for (int r = 0; r < 4; ++r)
          Cp[(long)(rbase + r) * DM + dcol] = (short)f2bf(a[r] + bi);
      } else {
        float bi = bias[col];
#pragma unroll
        for (int r = 0; r < 4; ++r) {
          long o = (long)(rbase + r) * N + col;
          Cf[o] = a[r] + bi + resid[o];
        }
      }
    }
  }
}

// ---------------- launch ----------------
extern "C" void kernel_launch(void* const* d_in, const int* in_sizes, int n_in,
                              void* d_out, int out_size, void* d_ws, size_t ws_size,
                              hipStream_t stream) {
  const float* x     = (const float*)d_in[0];
  const float* fd    = (const float*)d_in[1];
  const float* Wq    = (const float*)d_in[2];
  const float* bq    = (const float*)d_in[3];
  const float* Wk    = (const float*)d_in[4];
  const float* bk    = (const float*)d_in[5];
  const float* Wv    = (const float*)d_in[6];
  const float* bv    = (const float*)d_in[7];
  const float* Wo    = (const float*)d_in[8];
  const float* bo    = (const float*)d_in[9];
  const float* alpha = (const float*)d_in[10];
  const float* fsc   = (const float*)d_in[11];
  float* out = (float*)d_out;

  // --- workspace layout (~112 MB) ---
  char* wp = (char*)d_ws;
  auto alloc = [&](size_t bytes) {
    char* p = wp;
    wp += (bytes + 255) & ~(size_t)255;
    return p;
  };
  float* cos_tab = (float*)alloc(S * 4);
  float* c_arr   = (float*)alloc(S * 4);          // c_arr[0] = c0 bias factor
  float* g       = (float*)alloc(S * 4);
  float* wsm     = (float*)alloc((size_t)NB * NH * S * 4);   // 1 MB
  short* WTcat = (short*)alloc((size_t)4 * DM * DM * 2);  // Wq,Wk,Wv,Wo transposed
  short* WoT   = WTcat + (size_t)3 * DM * DM;
  short* slotA = (short*)alloc((size_t)NB * DS * 2);  // ABout -> V
  short* slotB = (short*)alloc((size_t)NB * DS * 2);  // Ge/Go -> Mc2 + A2t
  short* slotC = (short*)alloc((size_t)NB * DS * 2);  // Xs -> att_half

  // d_out scratch phases: uv (34.6MB) during G-phase; Q,K during attention
  short* uv = (short*)d_out;                        // [8][DM][KH2]
  short* Qn = (short*)d_out;                        // [(b,s)][DM] 33.5 MB
  short* Kn = (short*)d_out + (size_t)NB * DS;      // [(b,s)][DM] 33.5 MB

  short* Ge  = slotB;                               // [2][MEO][KH2] (Ge,Go)
  short* ABout = slotA;                             // [8][MEO][DM]
  short* Xs  = slotC;
  short* Vn  = slotA;                               // V natural (after ABout dead)
  short* Mc2 = slotB;                               // 9.73 MB (after Ge dead)
  short* A2t = (short*)((char*)slotB + 10u * 1024 * 1024);
  short* att_half = slotC;

  dim3 blk(256);

  // 1) tables+g   2) fold x + weight transposes + Ge/Go (merged)
  k_tabg<<<dim3(16 + S / 16), blk, 0, stream>>>(fd, alpha, fsc, cos_tab, c_arr, g);
  k_prep<<<dim3(49 + 54, 16, NB), blk, 0, stream>>>(x, uv, Wq, Wk, Wv, Wo, WTcat, g, Ge);

  // 3) even/odd spectral GEMM: AB[z] = (z<4 ? Ge : Go) @ uv[z]; 1024 wg, 2 blk/CU
  dim3 geo(DM / 128, MEO / 128, 8);
  gemm4<0, 0, 1><<<geo, blk, 0, stream>>>(Ge, uv, ABout, nullptr, nullptr, nullptr,
                                          nullptr, nullptr, nullptr, nullptr, nullptr,
                                          MEO, DM, KH2,
                                          (long)MEO * KH2, (long)DM * KH2, (long)MEO * DM);
  // 4) unfold mirror + row n=2048 into Xs [b][s][d]
  k_unfold2<<<dim3(8192), blk, 0, stream>>>(ABout, g, uv, Xs);

  // 5) fused q/k/v projections (EPI=4): 3072 wg of 128^2 tiles, 2 blk/CU
  dim3 gqkv(3 * DM / 128, MTOT / 128, 1);
  gemm4<4><<<gqkv, blk, 0, stream>>>(Xs, WTcat, Qn, Kn, Vn, nullptr,
                                     bq, bk, bv, c_arr, nullptr,
                                     MTOT, 3 * DM, DM, 0, 0, 0);

  // 6) fused logits + head-softmax   7) attend+fold + buildM2 (merged)
  k_logsoft<<<dim3(MTOT / 16), blk, 0, stream>>>(Qn, Kn, wsm);
  k_attfoldM2<<<dim3(33 + 38, DM / 64, NB), blk, 0, stream>>>(Vn, wsm, A2t, cos_tab, Mc2);

  // 8) att_time_half = Mc2 @ A2  (576 wg, 2 blk/CU — proven R16)
  dim3 ghalf(DM / 128, MH / 128, NB);
  gemm4<0><<<ghalf, blk, 0, stream>>>(Mc2, A2t, att_half, nullptr, nullptr, nullptr,
                                      nullptr, nullptr, nullptr, nullptr, nullptr,
                                      MH, DM, KH, 0, (long)DM * KH, (long)MH * DM);

  // 9) out = att_time @ Wo + bo + x  (AMIR mirror rows; 1024 wg)
  dim3 gproj(DM / 128, MTOT / 128, 1);
  gemm4<2, 1><<<gproj, blk, 0, stream>>>(att_half, WoT, nullptr, nullptr, nullptr, out,
                                         bo, nullptr, nullptr, nullptr, x,
                                         MTOT, DM, DM, 0, 0, 0);
}

// Round 18
// 384.234 us; speedup vs baseline: 1.0874x; 1.0874x over previous
//
#include <hip/hip_runtime.h>

// ---------------- constants ----------------
#define S      4096
#define DM     1024
#define NB     4
#define NH     16
#define HDIM   64
#define MTOT   (NB * S)          // 16384
#define DS     ((long)DM * S)    // 4,194,304
#define MH     2304              // padded half-rows for Mc2 (2049 used)
#define KH     2112              // folded K for Mc2 (2049 used)
#define KH2    2112              // folded K for even/odd G split (2049 used)
#define MEO    2048              // even/odd GEMM rows (n=0..2047; n=2048 special)

typedef __attribute__((ext_vector_type(8))) short short8;
typedef __attribute__((ext_vector_type(4))) float f32x4;
typedef __attribute__((ext_vector_type(8))) unsigned short u16x8;
typedef __attribute__((ext_vector_type(4))) unsigned short u16x4;

__device__ __forceinline__ unsigned short f2bf(float f) {
  union { float f; unsigned u; } v; v.f = f;
  unsigned r = v.u + 0x7fffu + ((v.u >> 16) & 1u);   // RNE
  return (unsigned short)(r >> 16);
}
__device__ __forceinline__ float bf2f(short h) {
  union { unsigned u; float f; } v; v.u = ((unsigned)(unsigned short)h) << 16;
  return v.f;
}

#define GLOAD(gp, lp) __builtin_amdgcn_global_load_lds( \
    (const __attribute__((address_space(1))) void*)(gp), \
    (__attribute__((address_space(3))) void*)(lp), 16, 0, 0)

#define SBAR() do { asm volatile("" ::: "memory"); __builtin_amdgcn_s_barrier(); \
                    asm volatile("" ::: "memory"); } while (0)
#define WAITL0() asm volatile("s_waitcnt lgkmcnt(0)" ::: "memory")

// LDS swizzle for 64B-row tiles: XOR byte bits 4-5 with row bits 1-2 (byte bits 7-8).
#define SWZ(o) ((o) ^ ((((o) >> 7) & 3) << 4))

// ---------------- small kernels ----------------

// merged tables + g (block-local tables; identical fp formulas -> deterministic)
__global__ void k_tabg(const float* __restrict__ fd, const float* __restrict__ alpha,
                       const float* __restrict__ fsc,
                       float* __restrict__ cos_tab, float* __restrict__ c_arr,
                       float* __restrict__ g) {
  const float twopi = 6.28318530717958647692f;
  float aa = alpha[0] + fsc[0] * (fd[0] - 1.5f);
  int bx = blockIdx.x;
  if (bx < 16) {
    int k = bx * 256 + threadIdx.x;
    cos_tab[k] = cosf(twopi * ((float)k / (float)S));
    int kk = (k <= S / 2) ? k : (S - k);
    float af = (float)kk / (float)S;
    c_arr[k] = cosf(aa * atanf(logf(af + 1e-10f)));
    return;
  }
  __shared__ float sct[S];
  __shared__ float sc[S];
  __shared__ float red[16][17];
  for (int i = threadIdx.x; i < S; i += 256) {
    sct[i] = cosf(twopi * ((float)i / (float)S));
    int kk = (i <= S / 2) ? i : (S - i);
    float af = (float)kk / (float)S;
    sc[i] = cosf(aa * atanf(logf(af + 1e-10f)));
  }
  __syncthreads();
  int jl = threadIdx.x >> 4, r = threadIdx.x & 15;
  int j = (bx - 16) * 16 + jl;
  float acc = 0.f;
#pragma unroll 4
  for (int i = 0; i < 256; ++i) {
    int k = r + 16 * i;
    acc += sc[k] * sct[(j * k) & (S - 1)];
  }
  red[jl][r] = acc;
  __syncthreads();
  if (r == 0) {
    float s = 0.f;
#pragma unroll
    for (int i = 0; i < 16; ++i) s += red[jl][i];
    g[j] = s * (1.f / (float)S);
  }
}

// merged foldT + transW4 + buildEO.
// bx<33: fold x->uv tile; 33<=bx<49: transW tile; bx>=49: Ge/Go chunk.
__global__ void k_prep(const float* __restrict__ x, short* __restrict__ uv,
                       const float* __restrict__ W0, const float* __restrict__ W1,
                       const float* __restrict__ W2, const float* __restrict__ W3,
                       short* __restrict__ WT,
                       const float* __restrict__ g, short* __restrict__ Ge) {
  __shared__ float sh[2 * 64 * 65];
  int bx = blockIdx.x, by = blockIdx.y, bz = blockIdx.z;
  int t = threadIdx.x;
  if (bx >= 49) {
    long lin = (long)(bx - 49) + 54L * (by + 16L * bz);
    long i8 = (lin * 256 + t) * 8;
    if (i8 >= (long)MEO * KH2) return;
    int n = (int)(i8 / KH2);
    int m = (int)(i8 % KH2);
    u16x8 ev, ov;
#pragma unroll
    for (int j = 0; j < 8; ++j) {
      int mm = m + j;
      float e, o;
      if (mm == 0)            { e = g[n]; o = 0.f; }
      else if (mm == 2048)    { e = g[(n + 2048) & (S - 1)]; o = 0.f; }
      else if (mm > 2048)     { e = 0.f; o = 0.f; }
      else {
        float a = g[(n - mm) & (S - 1)], b = g[(n + mm) & (S - 1)];
        e = 0.5f * (a + b); o = 0.5f * (a - b);
      }
      ev[j] = f2bf(e); ov[j] = f2bf(o);
    }
    *(u16x8*)(Ge + i8) = ev;
    *(u16x8*)(Ge + (long)MEO * KH2 + i8) = ov;
    return;
  }
  int r = t >> 4, c4 = (t & 15) * 4;
  if (bx >= 33) {
    float (*tile)[65] = (float(*)[65])sh;
    const float* W = (bz == 0) ? W0 : ((bz == 1) ? W1 : ((bz == 2) ? W2 : W3));
    short* WTo = WT + (size_t)bz * DM * DM;
    int k0 = (bx - 33) * 64, n0 = by * 64;
    const float* ip = W + (long)k0 * DM + n0;
#pragma unroll
    for (int rr = 0; rr < 4; ++rr) {
      float4 v = *(const float4*)(ip + (long)(r + rr * 16) * DM + c4);
      tile[r + rr * 16][c4 + 0] = v.x;
      tile[r + rr * 16][c4 + 1] = v.y;
      tile[r + rr * 16][c4 + 2] = v.z;
      tile[r + rr * 16][c4 + 3] = v.w;
    }
    __syncthreads();
    int k_loc = t & 63, nq = t >> 6;
    short* op = WTo + (long)n0 * DM + k0;
#pragma unroll
    for (int i = 0; i < 16; ++i) {
      int n_loc = nq * 16 + i;
      op[(long)n_loc * DM + k_loc] = (short)f2bf(tile[k_loc][n_loc]);
    }
    return;
  }
  float (*tp)[65] = (float(*)[65])sh;
  float (*tm)[65] = (float(*)[65])(sh + 64 * 65);
  int m0 = bx * 64, d0 = by * 64, b = bz;
#pragma unroll
  for (int rr = 0; rr < 4; ++rr) {
    int m = m0 + r + rr * 16;
    float4 vp = *(const float4*)(x + ((long)(b * S + m)) * DM + d0 + c4);
    int ms = (S - m) & (S - 1);
    float4 vm = *(const float4*)(x + ((long)(b * S + ms)) * DM + d0 + c4);
    tp[r + rr * 16][c4 + 0] = vp.x; tp[r + rr * 16][c4 + 1] = vp.y;
    tp[r + rr * 16][c4 + 2] = vp.z; tp[r + rr * 16][c4 + 3] = vp.w;
    tm[r + rr * 16][c4 + 0] = vm.x; tm[r + rr * 16][c4 + 1] = vm.y;
    tm[r + rr * 16][c4 + 2] = vm.z; tm[r + rr * 16][c4 + 3] = vm.w;
  }
  __syncthreads();
  int m_loc = t & 63, dq = t >> 6;
#pragma unroll
  for (int i = 0; i < 16; ++i) {
    int d_loc = dq * 16 + i;
    int m = m0 + m_loc;
    float P = tp[m_loc][d_loc], M = tm[m_loc][d_loc];
    float u, v;
    if (m == 0 || m == 2048) { u = P; v = 0.f; }
    else if (m > 2048)       { u = 0.f; v = 0.f; }
    else                     { u = P + M; v = P - M; }
    long base = ((long)(b * DM + d0 + d_loc)) * KH2 + m;
    uv[base] = (short)f2bf(u);
    uv[base + (long)4 * DM * KH2] = (short)f2bf(v);
  }
}

// merged: blocks [0,4096): unfold AB -> Xs; blocks [4096,8192): row n=2048 dot
__global__ void k_unfold2(const short* __restrict__ AB, const float* __restrict__ g,
                          const short* __restrict__ uv, short* __restrict__ Xs) {
  __shared__ float red[256];
  int bx = blockIdx.x;
  if (bx < 4096) {
    long i8 = ((long)bx * 256 + threadIdx.x) * 8;
    int b = (int)(i8 >> 21);             // MEO*DM = 2^21
    long rr = i8 & ((1L << 21) - 1);
    int n = (int)(rr >> 10);
    int d = (int)(rr & (DM - 1));
    u16x8 av = *(const u16x8*)(AB + i8);
    u16x8 bv = *(const u16x8*)(AB + ((long)4 * MEO * DM) + i8);
    u16x8 sv, dv;
#pragma unroll
    for (int j = 0; j < 8; ++j) {
      float A = bf2f((short)av[j]), B = bf2f((short)bv[j]);
      sv[j] = f2bf(A + B);
      dv[j] = f2bf(A - B);
    }
    *(u16x8*)(Xs + ((long)b * S + n) * DM + d) = sv;
    if (n > 0)
      *(u16x8*)(Xs + ((long)b * S + (S - n)) * DM + d) = dv;
  } else {
    int bd = bx - 4096;                  // 0..NB*DM-1
    int b = bd >> 10, d = bd & (DM - 1);
    const short* up = uv + ((long)(b * DM + d)) * KH2;
    int t = threadIdx.x;
    float acc = 0.f;
    for (int m = t; m <= 2048; m += 256)
      acc += g[2048 - m] * bf2f(up[m]);
    red[t] = acc;
    __syncthreads();
    for (int sh = 128; sh > 0; sh >>= 1) {
      if (t < sh) red[t] += red[t + sh];
      __syncthreads();
    }
    if (t == 0) Xs[((long)b * S + 2048) * DM + d] = (short)f2bf(red[0]);
  }
}

// fused logits+head-softmax. Q,K in natural [(b,s)][DM] layout.
__global__ void k_logsoft(const short* __restrict__ Q, const short* __restrict__ K,
                          float* __restrict__ w) {
  int idx = blockIdx.x * 16 + (threadIdx.x >> 4);   // (b,s) 0..16383
  int h = threadIdx.x & 15;
  const short* q = Q + (long)idx * DM + h * HDIM;
  const short* k = K + (long)idx * DM + h * HDIM;
  float acc = 0.f;
#pragma unroll
  for (int jj = 0; jj < 8; ++jj) {
    u16x8 qa = *(const u16x8*)(q + jj * 8);
    u16x8 ka = *(const u16x8*)(k + jj * 8);
#pragma unroll
    for (int l = 0; l < 8; ++l) acc += bf2f((short)qa[l]) * bf2f((short)ka[l]);
  }
  acc *= 0.125f;
  float m = acc;
#pragma unroll
  for (int d = 1; d < 16; d <<= 1) m = fmaxf(m, __shfl_xor(m, d, 16));
  float e = expf(acc - m);
  float ssum = e;
#pragma unroll
  for (int d = 1; d < 16; d <<= 1) ssum += __shfl_xor(ssum, d, 16);
  int b = idx >> 12, s = idx & (S - 1);
  w[((long)b * NH + h) * S + s] = e / ssum;
}

// merged attfold2 + buildM2. bx<33: attend+fold tile; bx>=33: buildM2 chunk.
__global__ void k_attfoldM2(const short* __restrict__ V, const float* __restrict__ wsm,
                            short* __restrict__ A2t,
                            const float* __restrict__ cos_tab, short* __restrict__ Mc2) {
  int bx = blockIdx.x, by = blockIdx.y, bz = blockIdx.z;
  if (bx >= 33) {
    long lin = (long)(bx - 33) + 38L * (by + 16L * bz);   // 0..2431
    long i8 = (lin * 256 + threadIdx.x) * 8;
    if (i8 >= (long)MH * KH) return;
    int n = (int)(i8 / KH);
    int m = (int)(i8 % KH);
    u16x8 mv;
#pragma unroll
    for (int j = 0; j < 8; ++j) {
      int mm = m + j;
      float vv = (mm <= 2048) ? cos_tab[(n * mm) & (S - 1)] * 0.015625f : 0.f;
      mv[j] = f2bf(vv);
    }
    *(u16x8*)(Mc2 + i8) = mv;
    return;
  }
  __shared__ float t1[64][65];
  __shared__ float t2[64][65];
  __shared__ float w1[64], w2[64];
  int m0 = bx * 64, d0 = by * 64, b = bz;
  int t = threadIdx.x;
  int h0 = d0 >> 6;
  if (t < 64) {
    int m = m0 + t;
    const float* wp = wsm + ((long)b * NH + h0) * S;
    w1[t] = wp[m & (S - 1)];
    w2[t] = wp[(S - m) & (S - 1)];
  }
  int r = t >> 4, c4 = (t & 15) * 4;
#pragma unroll
  for (int rr = 0; rr < 4; ++rr) {
    int i = r + rr * 16;
    int m = m0 + i;
    u16x4 a = *(const u16x4*)(V + ((long)(b * S + (m & (S - 1)))) * DM + d0 + c4);
    u16x4 bb = *(const u16x4*)(V + ((long)(b * S + ((S - m) & (S - 1)))) * DM + d0 + c4);
#pragma unroll
    for (int l = 0; l < 4; ++l) {
      t1[i][c4 + l] = bf2f((short)a[l]);
      t2[i][c4 + l] = bf2f((short)bb[l]);
    }
  }
  __syncthreads();
  int i_loc = t & 63, jq = t >> 6;
  int m = m0 + i_loc;
#pragma unroll
  for (int jj = 0; jj < 16; ++jj) {
    int j = jq * 16 + jj;
    float rv;
    if (m == 0 || m == 2048) rv = w1[i_loc] * t1[i_loc][j];
    else if (m < 2048)       rv = w1[i_loc] * t1[i_loc][j] + w2[i_loc] * t2[i_loc][j];
    else                     rv = 0.f;
    A2t[((long)(b * DM + d0 + j)) * KH + m] = (short)f2bf(rv);
  }
}

// ---------------- 256x256 8-phase GEMM (R13-proven) ----------------
template <int EPI, int AMIR = 0, int ASEL = 0, int WALK = 0, int MREP = 1>
__global__ __launch_bounds__(512, 2) void gemm8(
    const short* __restrict__ A, const short* __restrict__ Bt,
    short* __restrict__ Cb, short* __restrict__ Cb2, short* __restrict__ Cb3,
    float* __restrict__ Cf,
    const float* __restrict__ bias, const float* __restrict__ bias2,
    const float* __restrict__ bias3,
    const float* __restrict__ bsc, const float* __restrict__ resid,
    int M, int N, int K, long aBatch, long bBatch, long cBatch) {
  __shared__ __align__(16) short SH[65536];   // 128 KiB
  auto Ab = [&](int buf, int ks) { return SH + (buf * 2 + ks) * 8192; };
  auto Bb = [&](int buf, int ks) { return SH + 32768 + (buf * 2 + ks) * 8192; };

  const int gx = gridDim.x, gy = gridDim.y;
  const int nwg = gx * gy * gridDim.z;
  int lin = blockIdx.x + gx * (blockIdx.y + gy * blockIdx.z);
  int swz = lin;
  if ((nwg & 7) == 0) {
    const int cpx = nwg >> 3;
    swz = (lin & 7) * cpx + (lin >> 3);
  }
  const int NTN = N >> 8;
  const int NTM = M >> 8;
  const int tid = threadIdx.x;
  const int lane = tid & 63;
  const int wid = tid >> 6;
  const int wm = wid >> 2, wn = wid & 3;

  const int o0 = tid * 16, o1 = o0 + 8192;
  const int lo0 = SWZ(o0), lo1 = SWZ(o1);
  const int srow[2] = {lo0 >> 6, lo1 >> 6};
  const int scol[2] = {(lo0 & 63) >> 1, (lo1 & 63) >> 1};

  for (int rep = 0; rep < MREP; ++rep) {
    const int wg = swz + rep * nwg;
    int ntile, mtile, bz;
    if (WALK) {
      mtile = wg % NTM;
      const int rest = wg / NTM;
      ntile = rest % NTN;
      bz = rest / NTN;
    } else {
      ntile = wg % NTN;
      const int rest = wg / NTN;
      mtile = rest % NTM;
      bz = rest / NTM;
    }

    const short* Ag = ASEL ? (A + (long)(bz >> 2) * aBatch) : (A + (long)bz * aBatch);
    const short* Bg = Bt + (long)bz * bBatch;
    const int m0 = mtile << 8, n0 = ntile << 8;

    const short* bA[2];
    const short* bB[2];
#pragma unroll
    for (int j = 0; j < 2; ++j) {
      if (AMIR) {
        int grow = m0 + srow[j];
        int b_ = grow >> 12, s_ = grow & (S - 1);
        int sm = (s_ <= 2048) ? s_ : (4096 - s_);
        bA[j] = Ag + ((long)b_ * MH + sm) * K + scol[j];
      } else {
        bA[j] = Ag + (long)(m0 + srow[j]) * K + scol[j];
      }
      bB[j] = Bg + (long)(n0 + srow[j]) * K + scol[j];
    }

    f32x4 acc[8][4];
#pragma unroll
    for (int i = 0; i < 8; ++i)
#pragma unroll
      for (int j = 0; j < 4; ++j) acc[i][j] = (f32x4){0.f, 0.f, 0.f, 0.f};

    const int NT = K >> 6;
    auto stage = [&](int h) {
      const int tau = h >> 2, q = h & 3;
      const int ks = q >> 1;
      const long k0 = (long)tau * 64 + ks * 32;
      const int dbase = (q & 1) * 65536 + (((tau & 1) << 1) + ks) * 16384;
      const short* b0 = (q & 1) ? bB[0] : bA[0];
      const short* b1 = (q & 1) ? bB[1] : bA[1];
      GLOAD(b0 + k0, (short*)((char*)SH + dbase + o0));
      GLOAD(b1 + k0, (short*)((char*)SH + dbase + o1));
    };

    if (rep > 0) SBAR();
#pragma unroll
    for (int h = 0; h < 7; ++h) stage(h);
    asm volatile("s_waitcnt vmcnt(6)" ::: "memory");
    SBAR();

    short8 bf[4];
    for (int t = 0; t < NT; ++t) {
      const int buf = t & 1;
#pragma unroll
      for (int p = 0; p < 4; ++p) {
        const int ks = p >> 1, mh = p & 1;
        short8 af[4];
        {
          const short* Ah = Ab(buf, ks);
          const int kb = (lane >> 4) * 16;
          const int r0 = wm * 128 + mh * 64 + (lane & 15);
#pragma unroll
          for (int i = 0; i < 4; ++i) {
            int byte = (r0 + i * 16) * 64 + kb;
            byte = SWZ(byte);
            af[i] = *(const short8*)((const char*)Ah + byte);
          }
          if (mh == 0) {
            const short* Bh = Bb(buf, ks);
            const int c0 = wn * 64 + (lane & 15);
#pragma unroll
            for (int j = 0; j < 4; ++j) {
              int byte = (c0 + j * 16) * 64 + kb;
              byte = SWZ(byte);
              bf[j] = *(const short8*)((const char*)Bh + byte);
            }
          }
        }
        { const int h = 4 * t + p + 7; if (h < 4 * NT) stage(h); }
        SBAR();
        WAITL0();
        __builtin_amdgcn_s_setprio(1);
#pragma unroll
        for (int i = 0; i < 4; ++i)
#pragma unroll
          for (int j = 0; j < 4; ++j)
            acc[mh * 4 + i][j] = __builtin_amdgcn_mfma_f32_16x16x32_bf16(
                af[i], bf[j], acc[mh * 4 + i][j], 0, 0, 0);
        __builtin_amdgcn_s_setprio(0);
        if (p == 3) {
          if (t < NT - 2) {
            asm volatile("s_waitcnt vmcnt(6)" ::: "memory");
          } else if (t == NT - 2) {
            asm volatile("s_waitcnt vmcnt(0)" ::: "memory");
          }
        }
        SBAR();
      }
    }

    const int rl = (lane >> 4) << 2;
#pragma unroll
    for (int f = 0; f < 8; ++f) {
      const int rbase = m0 + wm * 128 + f * 16 + rl;
#pragma unroll
      for (int j = 0; j < 4; ++j) {
        const int col = n0 + wn * 64 + j * 16 + (lane & 15);
        f32x4 a = acc[f][j];
        if constexpr (EPI == 0) {
          short* cp = Cb + (long)bz * cBatch;
#pragma unroll
          for (int r = 0; r < 4; ++r)
            cp[(long)(rbase + r) * N + col] = (short)f2bf(a[r]);
        } else if constexpr (EPI == 4) {
          const int pidx = col >> 10;
          const int dcol = col & (DM - 1);
          short* Cp = (pidx == 0) ? Cb : ((pidx == 1) ? Cb2 : Cb3);
          const float* bp = (pidx == 0) ? bias : ((pidx == 1) ? bias2 : bias3);
          const float bi = bp[dcol] * (bsc ? bsc[0] : 1.f);
#pragma unroll
          for (int r = 0; r < 4; ++r)
            Cp[(long)(rbase + r) * DM + dcol] = (short)f2bf(a[r] + bi);
        } else {
          float bi = bias[col];
#pragma unroll
          for (int r = 0; r < 4; ++r) {
            long o = (long)(rbase + r) * N + col;
            Cf[o] = a[r] + bi + resid[o];
          }
        }
      }
    }
  }
}

// ---------------- 128x128 4-wave GEMM (64 KiB LDS -> 2 blocks/CU) ----------------
// Use only where A+B working set L2-fits (Mc2, final); NOT QKV (R17 fetch blowup).
template <int EPI, int AMIR = 0, int ASEL = 0>
__global__ __launch_bounds__(256, 2) void gemm4(
    const short* __restrict__ A, const short* __restrict__ Bt,
    short* __restrict__ Cb, short* __restrict__ Cb2, short* __restrict__ Cb3,
    float* __restrict__ Cf,
    const float* __restrict__ bias, const float* __restrict__ bias2,
    const float* __restrict__ bias3,
    const float* __restrict__ bsc, const float* __restrict__ resid,
    int M, int N, int K, long aBatch, long bBatch, long cBatch) {
  __shared__ __align__(16) short SH[32768];   // 64 KiB
  auto Ab = [&](int buf, int ks) { return SH + (buf * 2 + ks) * 4096; };
  auto Bb = [&](int buf, int ks) { return SH + 16384 + (buf * 2 + ks) * 4096; };

  const int gx = gridDim.x, gy = gridDim.y;
  const int nwg = gx * gy * gridDim.z;
  int lin = blockIdx.x + gx * (blockIdx.y + gy * blockIdx.z);
  int swz = lin;
  if ((nwg & 7) == 0) {
    const int cpx = nwg >> 3;
    swz = (lin & 7) * cpx + (lin >> 3);
  }
  const int NTN = N >> 7;
  const int NTM = M >> 7;
  const int ntile = swz % NTN;
  const int rest = swz / NTN;
  const int mtile = rest % NTM;
  const int bz = rest / NTM;

  const short* Ag = ASEL ? (A + (long)(bz >> 2) * aBatch) : (A + (long)bz * aBatch);
  const short* Bg = Bt + (long)bz * bBatch;
  const int m0 = mtile << 7, n0 = ntile << 7;
  const int tid = threadIdx.x;
  const int lane = tid & 63;
  const int wid = tid >> 6;
  const int wm = wid >> 1, wn = wid & 1;

  const int o0 = tid * 16, o1 = o0 + 4096;
  const int lo0 = SWZ(o0), lo1 = SWZ(o1);
  const int srow[2] = {lo0 >> 6, lo1 >> 6};
  const int scol[2] = {(lo0 & 63) >> 1, (lo1 & 63) >> 1};

  const short* bA[2];
  const short* bB[2];
#pragma unroll
  for (int j = 0; j < 2; ++j) {
    if (AMIR) {
      int grow = m0 + srow[j];
      int b_ = grow >> 12, s_ = grow & (S - 1);
      int sm = (s_ <= 2048) ? s_ : (4096 - s_);
      bA[j] = Ag + ((long)b_ * MH + sm) * K + scol[j];
    } else {
      bA[j] = Ag + (long)(m0 + srow[j]) * K + scol[j];
    }
    bB[j] = Bg + (long)(n0 + srow[j]) * K + scol[j];
  }

  f32x4 acc[4][4];
#pragma unroll
  for (int i = 0; i < 4; ++i)
#pragma unroll
    for (int j = 0; j < 4; ++j) acc[i][j] = (f32x4){0.f, 0.f, 0.f, 0.f};

  const int NT = K >> 6;
  auto stage = [&](int h) {
    const int tau = h >> 2, q = h & 3;
    const int ks = q >> 1;
    const long k0 = (long)tau * 64 + ks * 32;
    const int dbase = (q & 1) * 32768 + (((tau & 1) << 1) + ks) * 8192;
    const short* b0 = (q & 1) ? bB[0] : bA[0];
    const short* b1 = (q & 1) ? bB[1] : bA[1];
    GLOAD(b0 + k0, (short*)((char*)SH + dbase + o0));
    GLOAD(b1 + k0, (short*)((char*)SH + dbase + o1));
  };

#pragma unroll
  for (int h = 0; h < 7; ++h) stage(h);
  asm volatile("s_waitcnt vmcnt(6)" ::: "memory");
  SBAR();

  short8 bf[4];
  for (int t = 0; t < NT; ++t) {
    const int buf = t & 1;
#pragma unroll
    for (int p = 0; p < 4; ++p) {
      const int ks = p >> 1, mh = p & 1;
      short8 af[2];
      {
        const short* Ah = Ab(buf, ks);
        const int kb = (lane >> 4) * 16;
        const int r0 = wm * 64 + mh * 32 + (lane & 15);
#pragma unroll
        for (int i = 0; i < 2; ++i) {
          int byte = (r0 + i * 16) * 64 + kb;
          byte = SWZ(byte);
          af[i] = *(const short8*)((const char*)Ah + byte);
        }
        if (mh == 0) {
          const short* Bh = Bb(buf, ks);
          const int c0 = wn * 64 + (lane & 15);
#pragma unroll
          for (int j = 0; j < 4; ++j) {
            int byte = (c0 + j * 16) * 64 + kb;
            byte = SWZ(byte);
            bf[j] = *(const short8*)((const char*)Bh + byte);
          }
        }
      }
      { const int h = 4 * t + p + 7; if (h < 4 * NT) stage(h); }
      SBAR();
      WAITL0();
      __builtin_amdgcn_s_setprio(1);
#pragma unroll
      for (int i = 0; i < 2; ++i)
#pragma unroll
        for (int j = 0; j < 4; ++j)
          acc[mh * 2 + i][j] = __builtin_amdgcn_mfma_f32_16x16x32_bf16(
              af[i], bf[j], acc[mh * 2 + i][j], 0, 0, 0);
      __builtin_amdgcn_s_setprio(0);
      if (p == 3) {
        if (t < NT - 2) {
          asm volatile("s_waitcnt vmcnt(6)" ::: "memory");
        } else if (t == NT - 2) {
          asm volatile("s_waitcnt vmcnt(0)" ::: "memory");
        }
      }
      SBAR();
    }
  }

  const int rl = (lane >> 4) << 2;
#pragma unroll
  for (int f = 0; f < 4; ++f) {
    const int rbase = m0 + wm * 64 + f * 16 + rl;
#pragma unroll
    for (int j = 0; j < 4; ++j) {
      const int col = n0 + wn * 64 + j * 16 + (lane & 15);
      f32x4 a = acc[f][j];
      if constexpr (EPI == 0) {
        short* cp = Cb + (long)bz * cBatch;
#pragma unroll
        for (int r = 0; r < 4; ++r)
          cp[(long)(rbase + r) * N + col] = (short)f2bf(a[r]);
      } else {
        float bi = bias[col];
#pragma unroll
        for (int r = 0; r < 4; ++r) {
          long o = (long)(rbase + r) * N + col;
          Cf[o] = a[r] + bi + resid[o];
        }
      }
    }
  }
}

// ---------------- launch ----------------
extern "C" void kernel_launch(void* const* d_in, const int* in_sizes, int n_in,
                              void* d_out, int out_size, void* d_ws, size_t ws_size,
                              hipStream_t stream) {
  const float* x     = (const float*)d_in[0];
  const float* fd    = (const float*)d_in[1];
  const float* Wq    = (const float*)d_in[2];
  const float* bq    = (const float*)d_in[3];
  const float* Wk    = (const float*)d_in[4];
  const float* bk    = (const float*)d_in[5];
  const float* Wv    = (const float*)d_in[6];
  const float* bv    = (const float*)d_in[7];
  const float* Wo    = (const float*)d_in[8];
  const float* bo    = (const float*)d_in[9];
  const float* alpha = (const float*)d_in[10];
  const float* fsc   = (const float*)d_in[11];
  float* out = (float*)d_out;

  // --- workspace layout (~112 MB) ---
  char* wp = (char*)d_ws;
  auto alloc = [&](size_t bytes) {
    char* p = wp;
    wp += (bytes + 255) & ~(size_t)255;
    return p;
  };
  float* cos_tab = (float*)alloc(S * 4);
  float* c_arr   = (float*)alloc(S * 4);          // c_arr[0] = c0 bias factor
  float* g       = (float*)alloc(S * 4);
  float* wsm     = (float*)alloc((size_t)NB * NH * S * 4);   // 1 MB
  short* WTcat = (short*)alloc((size_t)4 * DM * DM * 2);  // Wq,Wk,Wv,Wo transposed
  short* WoT   = WTcat + (size_t)3 * DM * DM;
  short* slotA = (short*)alloc((size_t)NB * DS * 2);  // ABout -> V
  short* slotB = (short*)alloc((size_t)NB * DS * 2);  // Ge/Go -> Mc2 + A2t
  short* slotC = (short*)alloc((size_t)NB * DS * 2);  // Xs -> att_half

  // d_out scratch phases: uv (34.6MB) during G-phase; Q,K during attention
  short* uv = (short*)d_out;                        // [8][DM][KH2]
  short* Qn = (short*)d_out;                        // [(b,s)][DM] 33.5 MB
  short* Kn = (short*)d_out + (size_t)NB * DS;      // [(b,s)][DM] 33.5 MB

  short* Ge  = slotB;                               // [2][MEO][KH2] (Ge,Go)
  short* ABout = slotA;                             // [8][MEO][DM]
  short* Xs  = slotC;
  short* Vn  = slotA;                               // V natural (after ABout dead)
  short* Mc2 = slotB;                               // 9.73 MB (after Ge dead)
  short* A2t = (short*)((char*)slotB + 10u * 1024 * 1024);
  short* att_half = slotC;

  dim3 blk(256), blk8(512);

  // 1) tables+g   2) fold x + weight transposes + Ge/Go (merged)
  k_tabg<<<dim3(16 + S / 16), blk, 0, stream>>>(fd, alpha, fsc, cos_tab, c_arr, g);
  k_prep<<<dim3(49 + 54, 16, NB), blk, 0, stream>>>(x, uv, Wq, Wk, Wv, Wo, WTcat, g, Ge);

  // 3) even/odd spectral GEMM: AB[z] = (z<4 ? Ge : Go) @ uv[z]; 256 wg (gemm8)
  dim3 geo(DM / 256, MEO / 256, 8);
  gemm8<0, 0, 1><<<geo, blk8, 0, stream>>>(Ge, uv, ABout, nullptr, nullptr, nullptr,
                                           nullptr, nullptr, nullptr, nullptr, nullptr,
                                           MEO, DM, KH2,
                                           (long)MEO * KH2, (long)DM * KH2, (long)MEO * DM);
  // 4) unfold mirror + row n=2048 into Xs [b][s][d]
  k_unfold2<<<dim3(8192), blk, 0, stream>>>(ABout, g, uv, Xs);

  // 5) fused q/k/v projections (EPI=4), gemm8 persistent 256 blocks x 3 tiles
  gemm8<4, 0, 0, 0, 3><<<dim3(256), blk8, 0, stream>>>(
      Xs, WTcat, Qn, Kn, Vn, nullptr, bq, bk, bv, c_arr, nullptr,
      MTOT, 3 * DM, DM, 0, 0, 0);

  // 6) fused logits + head-softmax   7) attend+fold + buildM2 (merged)
  k_logsoft<<<dim3(MTOT / 16), blk, 0, stream>>>(Qn, Kn, wsm);
  k_attfoldM2<<<dim3(33 + 38, DM / 64, NB), blk, 0, stream>>>(Vn, wsm, A2t, cos_tab, Mc2);

  // 8) att_time_half = Mc2 @ A2  (gemm4, 576 wg, 2 blk/CU — proven R16)
  dim3 ghalf(DM / 128, MH / 128, NB);
  gemm4<0><<<ghalf, blk, 0, stream>>>(Mc2, A2t, att_half, nullptr, nullptr, nullptr,
                                      nullptr, nullptr, nullptr, nullptr, nullptr,
                                      MH, DM, KH, 0, (long)DM * KH, (long)MH * DM);

  // 9) out = att_time @ Wo + bo + x  (gemm4 AMIR: A 9.4MB + B 2MB L2-fit; 1024 wg)
  dim3 gproj(DM / 128, MTOT / 128, 1);
  gemm4<2, 1><<<gproj, blk, 0, stream>>>(att_half, WoT, nullptr, nullptr, nullptr, out,
                                         bo, nullptr, nullptr, nullptr, x,
                                         MTOT, DM, DM, 0, 0, 0);
}